// Round 7
// baseline (967.620 us; speedup 1.0000x reference)
//
#include <hip/hip_runtime.h>

// ---------------------------------------------------------------------------
// KacLayer: out = x @ (W^T + M) + b, where M = A2 diag(vec) A1 (Kac walks).
// numpy default_rng(4048)/default_rng(4049) replication — VERIFIED PARTS:
//   * PCG64 core + SeedSequence w/ SUBTRACTIVE mix (selftest passed r5/r6)
//   * consumption = 32-bit buffered Lemire (numpy random_bounded_uint64_fill
//     uses the 32-bit path when rng<=0xFFFFFFFF; next_uint32 buffers u64
//     LOW half first, then HIGH):
//       ii[k]  = u32[k] >> 22                      (2^32%1024==0: no reject)
//       off[k] = 1 + (u32[3072+k]*1023 >> 32), reject iff low32(u32*1023)<4
//       jj[k]  = (ii[k]+off[k]) & 1023
//       th[k]  = 2pi*((u64[3072+k] >> 11)*2^-53)   (buffer empty after ints)
// ---------------------------------------------------------------------------

#define NSTEPS 3072
#define NCHUNK 26
#define NRAW (256 * NCHUNK)   // 6656 u64 (need 6144 + rejection slack)

typedef __attribute__((ext_vector_type(8))) short short8;
typedef __attribute__((ext_vector_type(4))) float f32x4;

struct SchedEntry { unsigned int ij; float c; float s; unsigned int pad; };

// ---------------- 128-bit PCG64 (numpy-exact) ------------------------------
struct U128 { unsigned long long lo, hi; };

__device__ __forceinline__ U128 mul128(U128 a, U128 b) {
  U128 r;
  r.lo = a.lo * b.lo;
  r.hi = __umul64hi(a.lo, b.lo) + a.lo * b.hi + a.hi * b.lo;
  return r;
}
__device__ __forceinline__ U128 add128(U128 a, U128 b) {
  U128 r; r.lo = a.lo + b.lo;
  r.hi = a.hi + b.hi + ((r.lo < a.lo) ? 1ull : 0ull);
  return r;
}
__device__ __forceinline__ U128 pcg_mult() {
  return U128{4865540595714422341ull, 2549297995355413924ull};
}
__device__ __forceinline__ U128 pcg_step(U128 st, U128 inc) {
  return add128(mul128(st, pcg_mult()), inc);
}
__device__ __forceinline__ unsigned long long pcg_out(U128 st) {
  unsigned long long x = st.hi ^ st.lo;
  unsigned int rot = (unsigned int)(st.hi >> 58);
  return (x >> rot) | (x << ((64u - rot) & 63u));
}

// numpy SeedSequence(seed).generate_state(4, uint64) -> pcg64_srandom
__device__ void pcg_seed(unsigned int seedval, U128* st, U128* inc) {
  unsigned int pool[4];
  unsigned int hc = 0x43b0d7e5u;                 // INIT_A
  auto hashmix = [&hc](unsigned int v) {
    v ^= hc; hc *= 0x931e8875u; v *= hc; v ^= v >> 16; return v;  // MULT_A
  };
  auto mixf = [](unsigned int x, unsigned int y) {
    unsigned int r = x * 0xca01f9ddu - y * 0x4973f715u;  // SUBTRACT (randutils)
    r ^= r >> 16; return r;
  };
  pool[0] = hashmix(seedval);
  pool[1] = hashmix(0u); pool[2] = hashmix(0u); pool[3] = hashmix(0u);
  for (int s = 0; s < 4; ++s)
    for (int d = 0; d < 4; ++d)
      if (s != d) pool[d] = mixf(pool[d], hashmix(pool[s]));
  unsigned int gc = 0x8b51f9ddu;                 // INIT_B
  unsigned int wv[8];
  for (int k = 0; k < 8; ++k) {
    unsigned int dv = pool[k & 3];
    dv ^= gc; gc *= 0x58f38dedu; dv *= gc; dv ^= dv >> 16;        // MULT_B
    wv[k] = dv;
  }
  unsigned long long o0 = (unsigned long long)wv[0] | ((unsigned long long)wv[1] << 32);
  unsigned long long o1 = (unsigned long long)wv[2] | ((unsigned long long)wv[3] << 32);
  unsigned long long o2 = (unsigned long long)wv[4] | ((unsigned long long)wv[5] << 32);
  unsigned long long o3 = (unsigned long long)wv[6] | ((unsigned long long)wv[7] << 32);
  U128 initstate = { o1, o0 };   // PCG_128BIT_CONSTANT(v[0], v[1]): hi = v[0]
  U128 initseq   = { o3, o2 };
  U128 icc; icc.lo = (initseq.lo << 1) | 1ull;
  icc.hi = (initseq.hi << 1) | (initseq.lo >> 63);
  *inc = icc;
  U128 s0 = {0ull, 0ull};
  s0 = pcg_step(s0, icc);        // srandom: state=0; step; +=initstate; step
  s0 = add128(s0, initstate);
  s0 = pcg_step(s0, icc);
  *st = s0;
}

__device__ U128 pcg_advance(U128 st, U128 inc, unsigned long long delta) {
  U128 am = {1ull, 0ull}, ap = {0ull, 0ull};
  U128 cm = pcg_mult(), cp = inc;
  while (delta) {
    if (delta & 1ull) {
      am = mul128(am, cm);
      ap = add128(mul128(ap, cm), cp);
    }
    cp = mul128(add128(cm, U128{1ull, 0ull}), cp);
    cm = mul128(cm, cm);
    delta >>= 1;
  }
  return add128(mul128(st, am), ap);
}

__device__ __forceinline__ double first_draw(unsigned int seed) {
  U128 st, inc;
  pcg_seed(seed, &st, &inc);
  st = pcg_step(st, inc);
  return (double)(pcg_out(st) >> 11) * (1.0 / 9007199254740992.0);
}

__device__ __forceinline__ unsigned short f32_to_bf16(float f) {
  unsigned int u = __builtin_bit_cast(unsigned int, f);
  unsigned int r = u + 0x7fffu + ((u >> 16) & 1u);
  return (unsigned short)(r >> 16);
}
__device__ __forceinline__ float bf16_to_f32(unsigned short h) {
  return __builtin_bit_cast(float, (unsigned int)h << 16);
}

// ---------------- Kernel 1: schedule generation ----------------------------
__global__ __launch_bounds__(256) void gen_sched_kernel(SchedEntry* __restrict__ sched,
                                                        float* __restrict__ diag) {
  __shared__ unsigned long long raw[NRAW];
  __shared__ unsigned short s_iiv[NSTEPS];
  __shared__ int s_rej;
  __shared__ int s_p64;
  const int w = blockIdx.x;     // walk: seed 4048 + w
  const int t = threadIdx.x;

  // RNG selftest (majority-of-3; diag pre-zeroed via hipMemsetAsync)
  if (w == 0 && t == 0) {
    int m1 = first_draw(42u)    != 0.7739560485559633;
    int m2 = first_draw(0u)     != 0.6369616873214543;
    int m3 = first_draw(12345u) != 0.22733602246716966;
    if (m1 + m2 + m3 >= 2)
      diag[0] = 3.0e8f + (float)(m1 + 2 * m2 + 4 * m3) * 3.0e7f;
  }

  U128 st, inc;
  pcg_seed(4048u + (unsigned int)w, &st, &inc);
  U128 mine = pcg_advance(st, inc, (unsigned long long)t * NCHUNK);
  for (int q = 0; q < NCHUNK; ++q) {
    mine = pcg_step(mine, inc);
    raw[t * NCHUNK + q] = pcg_out(mine);
  }
  if (t == 0) s_rej = 0;
  __syncthreads();

  // u32 draw m: low half of u64 first, then high (pcg64_next32 buffering)
  auto u32at = [&](int m) -> unsigned int {
    unsigned long long v = raw[m >> 1];
    return (m & 1) ? (unsigned int)(v >> 32) : (unsigned int)v;
  };

  // Lemire-32(rng_excl=1023) rejects iff low32(u32*1023) < 4. Detect in parallel.
  for (int k = t; k < NSTEPS; k += 256) {
    unsigned long long m = (unsigned long long)u32at(NSTEPS + k) * 1023ull;
    if ((unsigned int)m < 4u) atomicAdd(&s_rej, 1);
  }
  __syncthreads();

  if (s_rej == 0) {
    // fast path: fixed consumption offsets
    for (int k = t; k < NSTEPS; k += 256) {
      unsigned int iv = u32at(k) >> 22;                 // (u32*1024)>>32
      unsigned long long m = (unsigned long long)u32at(NSTEPS + k) * 1023ull;
      unsigned int off = 1u + (unsigned int)(m >> 32);
      unsigned int jv = (iv + off) & 1023u;
      sched[w * NSTEPS + k].ij = (iv << 16) | jv;
    }
    if (t == 0) s_p64 = NSTEPS;        // 6144 u32 consumed -> u64 idx 3072
  } else if (t == 0) {
    // exact sequential replay with rejections (P ~ 3e-6 per walk)
    int p = 0;
    for (int k = 0; k < NSTEPS; ++k) s_iiv[k] = (unsigned short)(u32at(p++) >> 22);
    for (int k = 0; k < NSTEPS; ++k) {
      unsigned long long m = (unsigned long long)u32at(p++) * 1023ull;
      unsigned int lo = (unsigned int)m;
      if (lo < 1023u) {
        while (lo < 4u) { m = (unsigned long long)u32at(p++) * 1023ull; lo = (unsigned int)m; }
      }
      unsigned int off = 1u + (unsigned int)(m >> 32);
      unsigned int iv = s_iiv[k];
      unsigned int jv = (iv + off) & 1023u;
      sched[w * NSTEPS + k].ij = (iv << 16) | jv;
    }
    s_p64 = (p + 1) >> 1;              // ceil(u32_count/2): next fresh u64
  }
  __syncthreads();

  const int base = s_p64;
  for (int k = t; k < NSTEPS; k += 256) {
    unsigned long long v = raw[base + k];
    double d = (double)(v >> 11) * (1.0 / 9007199254740992.0);  // next_double
    double ang = d * 6.283185307179586;
    sched[w * NSTEPS + k].c = (float)cos(ang);
    sched[w * NSTEPS + k].s = (float)sin(ang);
  }
}

// ---------------- Kernel 2: Kac walk on identity + combine -----------------
// Block b tracks basis vectors e_{d0+r} in LDS L[1024 coords][16 rows]:
// after both phases L[c][r] = M[c, d0+r] (column d0+r of M = A2 D A1).
// Lane r (<16) owns row r entirely (reads/writes both coords): hazard-free.
__device__ void walk_phase(const SchedEntry* __restrict__ sch, float* L, int r) {
  #pragma unroll 4
  for (int g = 0; g < NSTEPS; ++g) {
    unsigned int ij = sch[g].ij;
    float c = sch[g].c, s = sch[g].s;
    int i = (int)(ij >> 16), j = (int)(ij & 0xffffu);
    float xi = L[i * 16 + r];
    float xj = L[j * 16 + r];
    L[i * 16 + r] = c * xi - s * xj;
    L[j * 16 + r] = s * xi + c * xj;
  }
}

__global__ __launch_bounds__(256) void walk_kernel(const SchedEntry* __restrict__ sched,
                                                   const float* __restrict__ W,
                                                   const float* __restrict__ vec,
                                                   unsigned short* __restrict__ Bh,
                                                   unsigned short* __restrict__ Bl,
                                                   float* __restrict__ diag) {
  __shared__ float L[1024 * 16];   // exactly 64 KB
  const int b = blockIdx.x;        // 0..63
  const int t = threadIdx.x;
  const int d0 = b * 16;
  for (int idx = t; idx < 1024 * 16; idx += 256) {
    int c = idx >> 4, r = idx & 15;
    L[idx] = (c == d0 + r) ? 1.0f : 0.0f;
  }
  __syncthreads();
  if (t < 16) walk_phase(sched, L, t);
  __syncthreads();
  {  // Givens chains preserve unit norms
    bool bad = false;
    if (t < 16) {
      float ss = 0.0f;
      for (int c = 0; c < 1024; ++c) { float v = L[c * 16 + t]; ss += v * v; }
      bad = fabsf(ss - 1.0f) > 2.0e-3f;
    }
    unsigned long long bm = __ballot(bad);
    if (b == 0 && t == 0 && bm) diag[1] = 2.0e7f;
  }
  __syncthreads();
  for (int idx = t; idx < 1024 * 16; idx += 256) L[idx] *= vec[idx >> 4];
  __syncthreads();
  if (t < 16) walk_phase(sched + NSTEPS, L, t);
  __syncthreads();
  // out = x @ (W+M)^T: B[e][d] = W[e][d] + M[e][d]; M[e][d0+dl] = L[e*16+dl]
  const int dl = t & 15;
  const int eb = t >> 4;
  for (int p = 0; p < 64; ++p) {
    int e = eb + p * 16;
    float wv = W[e * 1024 + d0 + dl];
    float pv = L[e * 16 + dl];
    float sum = wv + pv;
    unsigned short hi = f32_to_bf16(sum);
    float hif = bf16_to_f32(hi);
    unsigned short lo = f32_to_bf16(sum - hif);
    Bh[e * 1024 + d0 + dl] = hi;
    Bl[e * 1024 + d0 + dl] = lo;
  }
}

// ---------------- Kernel 3: split-bf16 GEMM out = x @ B^T + b --------------
// out = xh*Bh + xh*Bl + xl*Bh (xl*Bl term negligible).
__device__ __forceinline__ int swz(int row, int colbyte) {
  return row * 128 + (colbyte ^ ((row & 7) << 4));
}

__global__ __launch_bounds__(256) void gemm_kernel(const float* __restrict__ x,
                                                   const unsigned short* __restrict__ Bhg,
                                                   const unsigned short* __restrict__ Blg,
                                                   const float* __restrict__ bvec,
                                                   const float* __restrict__ diag,
                                                   float* __restrict__ out) {
  __shared__ unsigned short Ash[128 * 64];
  __shared__ unsigned short Asl[128 * 64];
  __shared__ unsigned short Bsh[128 * 64];
  __shared__ unsigned short Bsl[128 * 64];
  const int t = threadIdx.x;
  const int bm = blockIdx.x & 255;
  const int bn = blockIdx.x >> 8;
  const int m0 = bm * 128, n0 = bn * 128;
  const int l = t & 63, w = t >> 6;
  const int wr = w >> 1, wc = w & 1;
  const int lr = l & 15, lk = l >> 4;
  const int arb = t >> 4, akb = (t & 15) << 3;
  const int brb = t >> 3, bkb = (t & 7) << 4;

  f32x4 acc[4][4] = {};
  float4 ra[8];
  uint4 rbh[4], rbl[4];

  #pragma unroll
  for (int p = 0; p < 8; ++p)
    ra[p] = *(const float4*)&x[(size_t)(m0 + arb + p * 16) * 1024 + (akb >> 1)];
  #pragma unroll
  for (int p = 0; p < 4; ++p) {
    rbh[p] = *(const uint4*)&Bhg[(size_t)(n0 + brb + p * 32) * 1024 + (bkb >> 1)];
    rbl[p] = *(const uint4*)&Blg[(size_t)(n0 + brb + p * 32) * 1024 + (bkb >> 1)];
  }

  for (int kt = 0; kt < 16; ++kt) {
    #pragma unroll
    for (int p = 0; p < 8; ++p) {
      ushort4 hv, lv;
      float v0 = ra[p].x, v1 = ra[p].y, v2 = ra[p].z, v3 = ra[p].w;
      hv.x = f32_to_bf16(v0); lv.x = f32_to_bf16(v0 - bf16_to_f32(hv.x));
      hv.y = f32_to_bf16(v1); lv.y = f32_to_bf16(v1 - bf16_to_f32(hv.y));
      hv.z = f32_to_bf16(v2); lv.z = f32_to_bf16(v2 - bf16_to_f32(hv.z));
      hv.w = f32_to_bf16(v3); lv.w = f32_to_bf16(v3 - bf16_to_f32(hv.w));
      *(ushort4*)((char*)Ash + swz(arb + p * 16, akb)) = hv;
      *(ushort4*)((char*)Asl + swz(arb + p * 16, akb)) = lv;
    }
    #pragma unroll
    for (int p = 0; p < 4; ++p) {
      *(uint4*)((char*)Bsh + swz(brb + p * 32, bkb)) = rbh[p];
      *(uint4*)((char*)Bsl + swz(brb + p * 32, bkb)) = rbl[p];
    }
    __syncthreads();

    if (kt + 1 < 16) {
      const int k0 = (kt + 1) * 64;
      #pragma unroll
      for (int p = 0; p < 8; ++p)
        ra[p] = *(const float4*)&x[(size_t)(m0 + arb + p * 16) * 1024 + k0 + (akb >> 1)];
      #pragma unroll
      for (int p = 0; p < 4; ++p) {
        rbh[p] = *(const uint4*)&Bhg[(size_t)(n0 + brb + p * 32) * 1024 + k0 + (bkb >> 1)];
        rbl[p] = *(const uint4*)&Blg[(size_t)(n0 + brb + p * 32) * 1024 + k0 + (bkb >> 1)];
      }
    }

    #pragma unroll
    for (int kk = 0; kk < 64; kk += 32) {
      short8 ah[4], al[4], bh[4], bl[4];
      const int cb = kk * 2 + lk * 16;
      #pragma unroll
      for (int m4 = 0; m4 < 4; ++m4) {
        ah[m4] = *(const short8*)((const char*)Ash + swz(wr * 64 + m4 * 16 + lr, cb));
        al[m4] = *(const short8*)((const char*)Asl + swz(wr * 64 + m4 * 16 + lr, cb));
      }
      #pragma unroll
      for (int n4 = 0; n4 < 4; ++n4) {
        bh[n4] = *(const short8*)((const char*)Bsh + swz(wc * 64 + n4 * 16 + lr, cb));
        bl[n4] = *(const short8*)((const char*)Bsl + swz(wc * 64 + n4 * 16 + lr, cb));
      }
      #pragma unroll
      for (int m4 = 0; m4 < 4; ++m4)
        #pragma unroll
        for (int n4 = 0; n4 < 4; ++n4) {
          acc[m4][n4] = __builtin_amdgcn_mfma_f32_16x16x32_bf16(ah[m4], bh[n4], acc[m4][n4], 0, 0, 0);
          acc[m4][n4] = __builtin_amdgcn_mfma_f32_16x16x32_bf16(ah[m4], bl[n4], acc[m4][n4], 0, 0, 0);
          acc[m4][n4] = __builtin_amdgcn_mfma_f32_16x16x32_bf16(al[m4], bh[n4], acc[m4][n4], 0, 0, 0);
        }
    }
    __syncthreads();
  }

  #pragma unroll
  for (int n4 = 0; n4 < 4; ++n4) {
    const int col = n0 + wc * 64 + n4 * 16 + lr;
    const float bias = bvec[col];
    #pragma unroll
    for (int m4 = 0; m4 < 4; ++m4) {
      const int row = m0 + wr * 64 + m4 * 16 + lk * 4;
      #pragma unroll
      for (int q = 0; q < 4; ++q)
        out[(size_t)(row + q) * 1024 + col] = acc[m4][n4][q] + bias;
    }
  }

  if (blockIdx.x == 0 && t == 0) {
    float dg = diag[0] + diag[1];
    if (dg != 0.0f) out[0] += dg;
  }
}

__global__ void signal_kernel(float* out, float val) { out[0] = val; }

// ---------------------------------------------------------------------------
extern "C" void kernel_launch(void* const* d_in, const int* in_sizes, int n_in,
                              void* d_out, int out_size, void* d_ws, size_t ws_size,
                              hipStream_t stream) {
  const float* x    = (const float*)d_in[0];
  const float* W    = (const float*)d_in[1];
  const float* bvec = (const float*)d_in[2];
  const float* vec  = (const float*)d_in[3];
  float* out = (float*)d_out;

  const size_t MB = 1024 * 1024;
  const size_t need = 131072 + 4 * MB;   // diag+sched in first 128K, Bh, Bl
  if (ws_size < need) {
    signal_kernel<<<1, 1, 0, stream>>>(out, 4.0e8f + (float)(ws_size >> 20) * 1000.0f);
    return;
  }
  float* diag  = (float*)d_ws;
  SchedEntry* sched = (SchedEntry*)((char*)d_ws + 256);
  unsigned short* Bh = (unsigned short*)((char*)d_ws + 131072);
  unsigned short* Bl = (unsigned short*)((char*)d_ws + 131072 + 2 * MB);

  hipMemsetAsync(diag, 0, 256, stream);
  gen_sched_kernel<<<2, 256, 0, stream>>>(sched, diag);
  walk_kernel<<<64, 256, 0, stream>>>(sched, W, vec, Bh, Bl, diag);
  gemm_kernel<<<2048, 256, 0, stream>>>(x, Bh, Bl, bvec, diag, out);
}